// Round 7
// baseline (86.937 us; speedup 1.0000x reference)
//
#include <hip/hip_runtime.h>

#define D_MODEL 768
#define BN 64
#define LN_EPS 1e-5f
#define MFMA __builtin_amdgcn_mfma_f32_16x16x32_bf16

typedef __attribute__((ext_vector_type(8))) short bf16x8;
typedef __attribute__((ext_vector_type(4))) float f32x4;

static __device__ __forceinline__ unsigned short f2bf(float f) {
    unsigned int u = __float_as_uint(f);
    u = (u + 0x7FFFu + ((u >> 16) & 1u)) >> 16;
    return (unsigned short)u;
}
static __device__ __forceinline__ float bf2f(unsigned short u) {
    return __uint_as_float(((unsigned int)u) << 16);
}

// LDS-only barrier: completes local ops, leaves global loads/stores in flight
// (avoids the s_waitcnt vmcnt(0) a __syncthreads would force).
static __device__ __forceinline__ void barrier_lds() {
    asm volatile("s_waitcnt lgkmcnt(0)" ::: "memory");
    __builtin_amdgcn_s_barrier();
    asm volatile("" ::: "memory");
}

// prep: fold LN affine into wd; re-layout both weight mats fragment-linear
// (main-kernel weight loads become base + lane*16B = contiguous 1KB/instr).
__global__ void prep(const float* __restrict__ wd, const float* __restrict__ ln_w,
                     const float* __restrict__ ln_b, const float* __restrict__ b_down,
                     const float* __restrict__ wu,
                     unsigned short* __restrict__ wd2_frag, unsigned short* __restrict__ wu_frag,
                     float* __restrict__ S, float* __restrict__ bd2) {
    const int b = blockIdx.x;    // 0..63
    const int t = threadIdx.x;   // 0..63
    const int c = b;
    const int wv = c >> 4, cl = c & 15;
    float s = 0.f, sb = 0.f;
    #pragma unroll
    for (int i = 0; i < 12; ++i) {
        const int d = t + 64 * i;
        const float w0 = wd[c * D_MODEL + d];
        const float w2 = w0 * ln_w[d];
        s  += w2;
        sb += w0 * ln_b[d];
        const int ks = d >> 5, kg = (d >> 3) & 3, e = d & 7;
        wd2_frag[(((wv * 24 + ks) * 64) + kg * 16 + cl) * 8 + e] = f2bf(w2);
    }
    #pragma unroll
    for (int off = 1; off < 64; off <<= 1) {
        s  += __shfl_xor(s, off);
        sb += __shfl_xor(sb, off);
    }
    if (t == 0) { S[c] = s; bd2[c] = b_down[c] + sb; }
    #pragma unroll
    for (int i = 0; i < 12; ++i) {
        const int n = b * 12 + i;
        const float v = wu[n * BN + t];
        const int jj = n >> 4, nl = n & 15;
        const int h = t >> 5, kg = (t >> 3) & 3, e = t & 7;
        wu_frag[(((jj * 2 + h) * 64) + kg * 16 + nl) * 8 + e] = f2bf(v);
    }
}

static __device__ __forceinline__ void load12(const float* __restrict__ x, size_t gt0,
                                              int w, int lane, float4 (&v)[12]) {
    const float* base0 = x + (gt0 + (size_t)(w * 4)) * D_MODEL + lane * 4;
    #pragma unroll
    for (int p = 0; p < 4; ++p)
        #pragma unroll
        for (int sg = 0; sg < 3; ++sg)
            v[p * 3 + sg] = *(const float4*)(base0 + p * D_MODEL + sg * 256);
}

static __device__ __forceinline__ void stage_tile(const float4 (&v)[12], int w, int lane,
                                                  unsigned short* sX, float* sMu, float* sRs) {
    #pragma unroll
    for (int p = 0; p < 4; ++p) {
        const int r = w * 4 + p;
        float sum = 0.f, sq = 0.f;
        #pragma unroll
        for (int sg = 0; sg < 3; ++sg) {
            const float4 f = v[p * 3 + sg];
            sum += (f.x + f.y) + (f.z + f.w);
            sq  += (f.x * f.x + f.y * f.y) + (f.z * f.z + f.w * f.w);
        }
        #pragma unroll
        for (int off = 1; off < 64; off <<= 1) {
            sum += __shfl_xor(sum, off);
            sq  += __shfl_xor(sq, off);
        }
        if (lane == 0) {
            const float mu = sum * (1.f / D_MODEL);
            sMu[r] = mu;
            sRs[r] = rsqrtf(sq * (1.f / D_MODEL) - mu * mu + LN_EPS);
        }
        #pragma unroll
        for (int sg = 0; sg < 3; ++sg) {
            const float4 f = v[p * 3 + sg];
            ushort4 o;
            o.x = f2bf(f.x); o.y = f2bf(f.y); o.z = f2bf(f.z); o.w = f2bf(f.w);
            const int bytecol = ((sg * 256 + lane * 4) * 2) ^ ((r & 15) << 4);
            *(ushort4*)((char*)(sX + r * 768) + bytecol) = o;
        }
    }
}

static __device__ __forceinline__ f32x4 gemm1_mac(int w, int lane, int kg, int l16,
                                                  const unsigned short* __restrict__ wd2_frag,
                                                  const unsigned short* sX) {
    const unsigned short* bp = wd2_frag + ((size_t)(w * 24) * 64 + lane) * 8;
    const char* sxrow = (const char*)(sX + l16 * 768);
    f32x4 acc = {0.f, 0.f, 0.f, 0.f};
    #pragma unroll
    for (int ks = 0; ks < 24; ++ks) {
        const bf16x8 a = *(const bf16x8*)(sxrow + ((ks * 64 + kg * 16) ^ (l16 << 4)));
        const bf16x8 b = *(const bf16x8*)(bp + ks * 512);
        acc = MFMA(a, b, acc, 0, 0, 0);
    }
    return acc;
}

static __device__ __forceinline__ void gemm1_epi(f32x4 acc, int w, int kg, int l16,
                                                 float Sc, float bd,
                                                 const float* sMu, const float* sRs,
                                                 unsigned short (*sDown)[72]) {
    const int c = w * 16 + l16;
    #pragma unroll
    for (int r = 0; r < 4; ++r) {
        const int t = kg * 4 + r;
        const float vv = sRs[t] * (acc[r] - sMu[t] * Sc) + bd;
        sDown[t][c] = f2bf(vv > 0.f ? vv : 0.f);
    }
}

static __device__ __forceinline__ void gemm2_store(int w, int kg, int l16, size_t gt0,
                                                   const unsigned short* __restrict__ wu_frag,
                                                   const unsigned short* sX,
                                                   const unsigned short (*sDown)[72],
                                                   const float* sBup, int lane,
                                                   float* __restrict__ out) {
    const bf16x8 pb0 = *(const bf16x8*)&sDown[l16][kg * 8];
    const bf16x8 pb1 = *(const bf16x8*)&sDown[l16][32 + kg * 8];
    float* orow = out + (gt0 + l16) * D_MODEL;
    const char* sxrow = (const char*)(sX + l16 * 768);
    #pragma unroll 4
    for (int j = 0; j < 12; ++j) {
        const int jj = 4 * j + w;
        const unsigned short* ap = wu_frag + ((size_t)(jj * 2) * 64 + lane) * 8;
        const bf16x8 a0 = *(const bf16x8*)ap;
        const bf16x8 a1 = *(const bf16x8*)(ap + 512);
        f32x4 acc = {0.f, 0.f, 0.f, 0.f};
        acc = MFMA(a0, pb0, acc, 0, 0, 0);
        acc = MFMA(a1, pb1, acc, 0, 0, 0);
        const int oc = jj * 16 + kg * 4;
        const float4 bu = *(const float4*)(sBup + oc);             // LDS, not vmem
        const ushort4 xb = *(const ushort4*)(sxrow + ((oc * 2) ^ (l16 << 4)));
        float4 o;
        o.x = acc[0] + bu.x + bf2f(xb.x);
        o.y = acc[1] + bu.y + bf2f(xb.y);
        o.z = acc[2] + bu.z + bf2f(xb.z);
        o.w = acc[3] + bu.w + bf2f(xb.w);
        *(float4*)(orow + oc) = o;
    }
}

__global__ __launch_bounds__(256, 4) void adapter_kernel(
    const float* __restrict__ x,
    const unsigned short* __restrict__ wd2_frag, const float* __restrict__ S,
    const float* __restrict__ bd2,
    const unsigned short* __restrict__ wu_frag, const float* __restrict__ b_up,
    float* __restrict__ out)
{
    __shared__ __align__(16) unsigned short sX[16 * 768];
    __shared__ __align__(16) unsigned short sDown[16][72];
    __shared__ float sMu[16], sRs[16];
    __shared__ __align__(16) float sBup[D_MODEL];

    const int tid  = threadIdx.x;
    const int lane = tid & 63;
    const int w    = tid >> 6;
    const int kg   = lane >> 4;
    const int l16  = lane & 15;
    const size_t gtA = (size_t)blockIdx.x * 16;
    const size_t gtB = gtA + (size_t)gridDim.x * 16;

    // block-constant preloads (keeps all later non-weight vmem out of the queue)
    const int c = w * 16 + l16;
    const float Sc = S[c], bd = bd2[c];
    sBup[tid]       = b_up[tid];
    sBup[tid + 256] = b_up[tid + 256];
    sBup[tid + 512] = b_up[tid + 512];

    // ---- tile A: load + stage ----
    float4 vA[12];
    load12(x, gtA, w, lane, vA);
    stage_tile(vA, w, lane, sX, sMu, sRs);
    barrier_lds();                                   // BAR1 (covers sX, sMu/sRs, sBup)

    // ---- tile A GEMM1 (weight loads issue first), then prefetch tile B ----
    f32x4 acc1 = gemm1_mac(w, lane, kg, l16, wd2_frag, sX);
    __builtin_amdgcn_sched_barrier(0);
    float4 vB[12];
    load12(x, gtB, w, lane, vB);                     // prefetch: in flight across BAR2/3
    __builtin_amdgcn_sched_barrier(0);
    gemm1_epi(acc1, w, kg, l16, Sc, bd, sMu, sRs, sDown);
    barrier_lds();                                   // BAR2 (no vmcnt drain)

    gemm2_store(w, kg, l16, gtA, wu_frag, sX, sDown, sBup, lane, out);
    barrier_lds();                                   // BAR3 (sX/sDown reads done)

    // ---- tile B ----
    stage_tile(vB, w, lane, sX, sMu, sRs);           // vmcnt waits only here
    barrier_lds();                                   // BAR4
    f32x4 acc2 = gemm1_mac(w, lane, kg, l16, wd2_frag, sX);
    gemm1_epi(acc2, w, kg, l16, Sc, bd, sMu, sRs, sDown);
    barrier_lds();                                   // BAR5
    gemm2_store(w, kg, l16, gtB, wu_frag, sX, sDown, sBup, lane, out);
}

extern "C" void kernel_launch(void* const* d_in, const int* in_sizes, int n_in,
                              void* d_out, int out_size, void* d_ws, size_t ws_size,
                              hipStream_t stream) {
    const float* x      = (const float*)d_in[0];
    const float* ln_w   = (const float*)d_in[1];
    const float* ln_b   = (const float*)d_in[2];
    const float* w_down = (const float*)d_in[3];
    const float* b_down = (const float*)d_in[4];
    const float* w_up   = (const float*)d_in[5];
    const float* b_up   = (const float*)d_in[6];
    float* out = (float*)d_out;

    unsigned short* wd2_frag = (unsigned short*)d_ws;            // 64*768 ush
    unsigned short* wu_frag  = wd2_frag + BN * D_MODEL;          // 768*64 ush
    float* S   = (float*)((char*)d_ws + 2 * BN * D_MODEL * sizeof(unsigned short));
    float* bd2 = S + BN;

    prep<<<BN, 64, 0, stream>>>(w_down, ln_w, ln_b, b_down, w_up, wd2_frag, wu_frag, S, bd2);

    const int tokens = in_sizes[0] / D_MODEL;   // 32768
    const int grid = tokens / 32;               // 1024 blocks x 2 tiles of 16
    adapter_kernel<<<grid, 256, 0, stream>>>(x, wd2_frag, S, bd2, wu_frag, b_up, out);
}

// Round 8
// 66.147 us; speedup vs baseline: 1.3143x; 1.3143x over previous
//
#include <hip/hip_runtime.h>

#define D_MODEL 768
#define BN 64
#define LN_EPS 1e-5f
#define MFMA __builtin_amdgcn_mfma_f32_16x16x32_bf16

typedef __attribute__((ext_vector_type(8))) short bf16x8;
typedef __attribute__((ext_vector_type(4))) float f32x4;

static __device__ __forceinline__ unsigned short f2bf(float f) {
    unsigned int u = __float_as_uint(f);
    u = (u + 0x7FFFu + ((u >> 16) & 1u)) >> 16;
    return (unsigned short)u;
}
static __device__ __forceinline__ float bf2f(unsigned short u) {
    return __uint_as_float(((unsigned int)u) << 16);
}

// prep: fold LN affine into wd; re-layout both weight mats fragment-linear
// (main-kernel weight loads become base + lane*16B = contiguous 1KB/instr).
__global__ void prep(const float* __restrict__ wd, const float* __restrict__ ln_w,
                     const float* __restrict__ ln_b, const float* __restrict__ b_down,
                     const float* __restrict__ wu,
                     unsigned short* __restrict__ wd2_frag, unsigned short* __restrict__ wu_frag,
                     float* __restrict__ S, float* __restrict__ bd2) {
    const int b = blockIdx.x;    // 0..63
    const int t = threadIdx.x;   // 0..63
    const int c = b;
    const int wv = c >> 4, cl = c & 15;
    float s = 0.f, sb = 0.f;
    #pragma unroll
    for (int i = 0; i < 12; ++i) {
        const int d = t + 64 * i;
        const float w0 = wd[c * D_MODEL + d];
        const float w2 = w0 * ln_w[d];
        s  += w2;
        sb += w0 * ln_b[d];
        const int ks = d >> 5, kg = (d >> 3) & 3, e = d & 7;
        wd2_frag[(((wv * 24 + ks) * 64) + kg * 16 + cl) * 8 + e] = f2bf(w2);
    }
    #pragma unroll
    for (int off = 1; off < 64; off <<= 1) {
        s  += __shfl_xor(s, off);
        sb += __shfl_xor(sb, off);
    }
    if (t == 0) { S[c] = s; bd2[c] = b_down[c] + sb; }
    #pragma unroll
    for (int i = 0; i < 12; ++i) {
        const int n = b * 12 + i;
        const float v = wu[n * BN + t];
        const int jj = n >> 4, nl = n & 15;
        const int h = t >> 5, kg = (t >> 3) & 3, e = t & 7;
        wu_frag[(((jj * 2 + h) * 64) + kg * 16 + nl) * 8 + e] = f2bf(v);
    }
}

// 512 threads, 32 tokens/block, 8 waves each doing R6-shaped work.
__global__ __launch_bounds__(512, 6) void adapter_kernel(
    const float* __restrict__ x,
    const unsigned short* __restrict__ wd2_frag, const float* __restrict__ S,
    const float* __restrict__ bd2,
    const unsigned short* __restrict__ wu_frag, const float* __restrict__ b_up,
    float* __restrict__ out)
{
    __shared__ __align__(16) unsigned short sX[32 * 768];    // 49152 B, XOR-swizzled
    __shared__ __align__(16) unsigned short sDown[32][72];   // 4608 B
    __shared__ float sMu[32], sRs[32];                       // 256 B  (total 54016 -> 3 blk/CU)

    const int tid  = threadIdx.x;
    const int lane = tid & 63;
    const int w    = tid >> 6;       // wave 0..7
    const int kg   = lane >> 4;
    const int l16  = lane & 15;
    const int cq   = w & 3;          // col-quarter (GEMM1) / col-phase (GEMM2)
    const int rt   = w >> 2;         // row-half: tokens rt*16 .. rt*16+15
    const size_t gt0 = (size_t)blockIdx.x * 32;

    // ---------- Phase 1: wave-contiguous x pass (wave owns rows w*4..w*4+3) ----------
    float4 v[12];
    {
        const float* base0 = x + (gt0 + (size_t)(w * 4)) * D_MODEL + lane * 4;
        #pragma unroll
        for (int p = 0; p < 4; ++p)
            #pragma unroll
            for (int sg = 0; sg < 3; ++sg)
                v[p * 3 + sg] = *(const float4*)(base0 + p * D_MODEL + sg * 256);
    }
    // preload GEMM2 j=0 weight frags (latency hides under phases 1-2)
    const unsigned short* ap0 = wu_frag + ((size_t)(cq * 2) * 64 + lane) * 8;
    const bf16x8 a0p = *(const bf16x8*)ap0;
    const bf16x8 a1p = *(const bf16x8*)(ap0 + 512);
    // block-constant epilogue scalars
    const int c = cq * 16 + l16;
    const float Sc = S[c], bd = bd2[c];

    #pragma unroll
    for (int p = 0; p < 4; ++p) {
        const int r = w * 4 + p;
        float sum = 0.f, sq = 0.f;
        #pragma unroll
        for (int sg = 0; sg < 3; ++sg) {
            const float4 f = v[p * 3 + sg];
            sum += (f.x + f.y) + (f.z + f.w);
            sq  += (f.x * f.x + f.y * f.y) + (f.z * f.z + f.w * f.w);
        }
        #pragma unroll
        for (int off = 1; off < 64; off <<= 1) {
            sum += __shfl_xor(sum, off);
            sq  += __shfl_xor(sq, off);
        }
        if (lane == 0) {
            const float mu = sum * (1.f / D_MODEL);
            sMu[r] = mu;
            sRs[r] = rsqrtf(sq * (1.f / D_MODEL) - mu * mu + LN_EPS);
        }
        #pragma unroll
        for (int sg = 0; sg < 3; ++sg) {
            const float4 f = v[p * 3 + sg];
            ushort4 o;
            o.x = f2bf(f.x); o.y = f2bf(f.y); o.z = f2bf(f.z); o.w = f2bf(f.w);
            const int bytecol = ((sg * 256 + lane * 4) * 2) ^ ((r & 15) << 4);
            *(ushort4*)((char*)(sX + r * 768) + bytecol) = o;
        }
    }
    __syncthreads();

    // ---------- Phase 2: GEMM1 on (row-half rt, col-quarter cq) ----------
    {
        const unsigned short* bp = wd2_frag + ((size_t)(cq * 24) * 64 + lane) * 8;
        const char* sxrow = (const char*)(sX + (rt * 16 + l16) * 768);
        f32x4 acc = {0.f, 0.f, 0.f, 0.f};
        #pragma unroll
        for (int ks = 0; ks < 24; ++ks) {
            const bf16x8 a = *(const bf16x8*)(sxrow + ((ks * 64 + kg * 16) ^ (l16 << 4)));
            const bf16x8 b = *(const bf16x8*)(bp + ks * 512);
            acc = MFMA(a, b, acc, 0, 0, 0);
        }
        #pragma unroll
        for (int r = 0; r < 4; ++r) {
            const int t = rt * 16 + kg * 4 + r;
            const float vv = sRs[t] * (acc[r] - sMu[t] * Sc) + bd;
            sDown[t][c] = f2bf(vv > 0.f ? vv : 0.f);
        }
    }
    __syncthreads();

    // ---------- Phase 3: GEMM2 swapped on row-half rt, col-tiles jj = 4j+cq ----------
    {
        const bf16x8 pb0 = *(const bf16x8*)&sDown[rt * 16 + l16][kg * 8];
        const bf16x8 pb1 = *(const bf16x8*)&sDown[rt * 16 + l16][32 + kg * 8];
        float* orow = out + (gt0 + rt * 16 + l16) * D_MODEL;
        const char* sxrow = (const char*)(sX + (rt * 16 + l16) * 768);
        #pragma unroll 4
        for (int j = 0; j < 12; ++j) {
            const int jj = 4 * j + cq;
            bf16x8 a0, a1;
            if (j == 0) { a0 = a0p; a1 = a1p; }
            else {
                const unsigned short* ap = wu_frag + ((size_t)(jj * 2) * 64 + lane) * 8;
                a0 = *(const bf16x8*)ap;
                a1 = *(const bf16x8*)(ap + 512);
            }
            f32x4 acc = {0.f, 0.f, 0.f, 0.f};
            acc = MFMA(a0, pb0, acc, 0, 0, 0);
            acc = MFMA(a1, pb1, acc, 0, 0, 0);
            const int oc = jj * 16 + kg * 4;
            const float4 bu = *(const float4*)(b_up + oc);
            const ushort4 xb = *(const ushort4*)(sxrow + ((oc * 2) ^ (l16 << 4)));
            float4 o;
            o.x = acc[0] + bu.x + bf2f(xb.x);
            o.y = acc[1] + bu.y + bf2f(xb.y);
            o.z = acc[2] + bu.z + bf2f(xb.z);
            o.w = acc[3] + bu.w + bf2f(xb.w);
            *(float4*)(orow + oc) = o;
        }
    }
}

extern "C" void kernel_launch(void* const* d_in, const int* in_sizes, int n_in,
                              void* d_out, int out_size, void* d_ws, size_t ws_size,
                              hipStream_t stream) {
    const float* x      = (const float*)d_in[0];
    const float* ln_w   = (const float*)d_in[1];
    const float* ln_b   = (const float*)d_in[2];
    const float* w_down = (const float*)d_in[3];
    const float* b_down = (const float*)d_in[4];
    const float* w_up   = (const float*)d_in[5];
    const float* b_up   = (const float*)d_in[6];
    float* out = (float*)d_out;

    unsigned short* wd2_frag = (unsigned short*)d_ws;            // 64*768 ush
    unsigned short* wu_frag  = wd2_frag + BN * D_MODEL;          // 768*64 ush
    float* S   = (float*)((char*)d_ws + 2 * BN * D_MODEL * sizeof(unsigned short));
    float* bd2 = S + BN;

    prep<<<BN, 64, 0, stream>>>(w_down, ln_w, ln_b, b_down, w_up, wd2_frag, wu_frag, S, bd2);

    const int tokens = in_sizes[0] / D_MODEL;   // 32768
    const int grid = tokens / 32;               // 1024 blocks of 32 tokens
    adapter_kernel<<<grid, 512, 0, stream>>>(x, wd2_frag, S, bd2, wu_frag, b_up, out);
}